// Round 2
// 111.922 us; speedup vs baseline: 1.0573x; 1.0573x over previous
//
#include <hip/hip_runtime.h>
#include <math.h>

// Problem constants: C=256, H=W=128, PH=PW=8.
#define C_ 256
#define H_ 128
#define W_ 128
#define PH_ 8
#define PW_ 8
#define HW_ (H_ * W_)
#define M3ROWS (H_ - 8 + 1)   // 121 sliding-window rows

typedef unsigned short u16;
typedef u16 u16x4 __attribute__((ext_vector_type(4)));
typedef u16 u16x8 __attribute__((ext_vector_type(8)));

__device__ __forceinline__ u16x8 kmax(u16x8 a, u16x8 b) {
    return __builtin_elementwise_max(a, b);
}

// fp32 -> bf16 (RNE) -> monotone-mapped u16 key (unsigned order == float order)
__device__ __forceinline__ u16 f32_to_key(float f) {
    unsigned u = __float_as_uint(f);
    unsigned r = (u + 0x7fffu + ((u >> 16) & 1u)) >> 16;   // RNE to bf16
    u16 b = (u16)r;
    return (b & 0x8000u) ? (u16)~b : (u16)(b | 0x8000u);
}
__device__ __forceinline__ float key_to_f32(u16 k) {
    u16 b = (k & 0x8000u) ? (u16)(k & 0x7fffu) : (u16)~k;
    return __uint_as_float(((unsigned)b) << 16);
}

// ---------- Kernel 1: (C,H*W) fp32 -> blocked (8 cg, H*W, 32ch) u16 keys ----
__global__ __launch_bounds__(256) void transpose_kernel(
    const float* __restrict__ fm, u16* __restrict__ fmt)
{
    __shared__ float tile[32 * 257];
    const int tid = threadIdx.x;
    const int g   = blockIdx.x & 7;
    const int hwb = blockIdx.x >> 3;
    const int c0  = g * 32;
    const int hw0 = hwb * 256;

    const int l    = tid & 63;
    const int crow = tid >> 6;
    const int sw   = (l >> 3) & 3;
    #pragma unroll
    for (int k = 0; k < 8; ++k) {
        const int c = crow + 4 * k;
        const float4 v = *(const float4*)(fm + (size_t)(c0 + c) * HW_ + hw0 + 4 * l);
        float* t = tile + c * 257 + 4 * l;
        t[(0 + sw) & 3] = v.x;
        t[(1 + sw) & 3] = v.y;
        t[(2 + sw) & 3] = v.z;
        t[(3 + sw) & 3] = v.w;
    }
    __syncthreads();

    u16* dst = fmt + (size_t)g * HW_ * 32;
    const int cq  = tid & 7;
    const int hwr = tid >> 3;
    #pragma unroll
    for (int m = 0; m < 8; ++m) {
        const int hw = hwr + 32 * m;
        const int o  = (hw & ~3) | (((hw & 3) + m) & 3);
        u16x4 w;
        w.x = f32_to_key(tile[(4 * cq + 0) * 257 + o]);
        w.y = f32_to_key(tile[(4 * cq + 1) * 257 + o]);
        w.z = f32_to_key(tile[(4 * cq + 2) * 257 + o]);
        w.w = f32_to_key(tile[(4 * cq + 3) * 257 + o]);
        *(u16x4*)(dst + (size_t)(hw0 + hw) * 32 + 4 * cq) = w;
    }
}

// ---------- Vertical sliding 8-row max body: dst[i] = max(src rows [i,i+8)) --
// All tables share the full [128 rows][128 cols][32 ch] layout per cg; only
// rows 0..120 of dst are written (rest unused).  128 blocks:
// bid = (seg<<6) | (band<<3) | cg.
__device__ __forceinline__ void vslide_body(
    const u16* __restrict__ src, u16* __restrict__ dst, int bid)
{
    const int g    = bid & 7;
    const int band = (bid >> 3) & 7;
    const int seg  = bid >> 6;          // 0..1
    const int i0   = band * 16;
    const int t    = threadIdx.x;
    const int co   = (t & 3) << 3;
    const int w    = (t >> 2) + 64 * seg;

    const u16* s = src + (size_t)g * HW_ * 32;
    u16*       d = dst + (size_t)g * HW_ * 32;
    const size_t RS = (size_t)W_ * 32;
    const size_t cofs = (size_t)w * 32 + co;

    u16x8 r[8];
    #pragma unroll
    for (int k = 0; k < 7; ++k)
        r[k] = *(const u16x8*)(s + (size_t)(i0 + k) * RS + cofs);
    #pragma unroll
    for (int j = 0; j < 16; ++j) {
        const int i = i0 + j;
        if (i < M3ROWS) {
            r[(j + 7) & 7] = *(const u16x8*)(s + (size_t)(i + 7) * RS + cofs);
            u16x8 m01 = kmax(r[0], r[1]);
            u16x8 m23 = kmax(r[2], r[3]);
            u16x8 m45 = kmax(r[4], r[5]);
            u16x8 m67 = kmax(r[6], r[7]);
            *(u16x8*)(d + (size_t)i * RS + cofs) =
                kmax(kmax(m01, m23), kmax(m45, m67));
        }
    }
}

// ---------- Horizontal sliding 8-col max body: dst[h][j] = max(src[h][j..j+8))
// 64 blocks: mbid = (jseg<<4) | (hband<<3) | cg.  Cols j in [0,121).
__device__ __forceinline__ void mw_body(
    const u16* __restrict__ src, u16* __restrict__ dst, int mbid)
{
    const int g     = mbid & 7;
    const int hband = (mbid >> 3) & 1;
    const int jseg  = mbid >> 4;        // 0..3
    const int t     = threadIdx.x;
    const int co    = (t & 3) << 3;
    const int h     = hband * 64 + (t >> 2);

    const int j0   = jseg * 31;
    const int jcnt = min(31, M3ROWS - j0);   // 31,31,31,28

    const size_t RS = (size_t)W_ * 32;
    const u16* s = src + (size_t)g * HW_ * 32 + (size_t)h * RS + co;
    u16*       d = dst + (size_t)g * HW_ * 32 + (size_t)h * RS + co;

    u16x8 r[8];
    #pragma unroll
    for (int k = 0; k < 7; ++k)
        r[k] = *(const u16x8*)(s + (size_t)(j0 + k) * 32);
    #pragma unroll
    for (int jj = 0; jj < 31; ++jj) {
        if (jj < jcnt) {
            r[(jj + 7) & 7] = *(const u16x8*)(s + (size_t)(j0 + jj + 7) * 32);
            u16x8 m01 = kmax(r[0], r[1]);
            u16x8 m23 = kmax(r[2], r[3]);
            u16x8 m45 = kmax(r[4], r[5]);
            u16x8 m67 = kmax(r[6], r[7]);
            *(u16x8*)(d + (size_t)(j0 + jj) * 32) =
                kmax(kmax(m01, m23), kmax(m45, m67));
        }
    }
}

// ---------- Kernel 2: m3 = vslide8(fmt)  (128 blocks)  +  mw = hslide8(fmt) --
__global__ __launch_bounds__(256) void k2_kernel(
    const u16* __restrict__ fmt, u16* __restrict__ m3, u16* __restrict__ mw)
{
    const int bid = blockIdx.x;
    if (bid < 128) vslide_body(fmt, m3, bid);
    else           mw_body(fmt, mw, bid - 128);
}

// ---------- Kernel 3: m8 = vslide8(mw)  (2-D 8x8 max) ----------
__global__ __launch_bounds__(256) void k3_kernel(
    const u16* __restrict__ mw, u16* __restrict__ m8)
{
    vslide_body(mw, m8, blockIdx.x);
}

// ---------- Kernel 4: pool — one lane = one (ph,pw) bin x 8 channels ----------
// Tables at offsets {0,T,2T,3T} = {fmt, m3, mw, m8}; any bin side L:
//   L>=8 : 2 overlapping 8-spans {a, b-8} (+ a+5 if L==17)
//   L<8  : L singles
// so table = base + rsp*T + csp*2T and the bin is rn*cn loads (typ. 4).
__global__ __launch_bounds__(256) void pool2_kernel(
    const u16* __restrict__ tabs, const int* __restrict__ rois,
    float* __restrict__ out, int N)
{
    const int bid  = blockIdx.x;
    const int cg   = bid & 7;            // XCD-affine channel group
    const int n    = bid >> 3;
    const int w    = threadIdx.x >> 6;   // channel oct within cg
    const int lane = threadIdx.x & 63;
    const int ph   = lane >> 3;
    const int pw   = lane & 7;
    const int co   = w << 3;

    const int4 roi = ((const int4*)rois)[n];
    const int y = roi.x, x = roi.y, rH = roi.z, rW = roi.w;

    const int hs  = (ph * rH) >> 3;
    const int he  = ((ph + 1) * rH + 7) >> 3;
    const int ws_ = (pw * rW) >> 3;
    const int we  = ((pw + 1) * rW + 7) >> 3;
    const int a = y + hs, b = y + he, L = he - hs;     // L in [1,17]
    const int wa = x + ws_, wb = x + we, Wd = we - ws_;

    const size_t T  = (size_t)HW_ * C_;
    const size_t RS = (size_t)W_ * 32;
    const u16* pl = tabs + (size_t)cg * (HW_ * 32) + co;

    const int rsp = (L >= 8), csp = (Wd >= 8);
    const int rn = rsp ? ((L > 16) ? 3 : 2) : L;
    const int cn = csp ? ((Wd > 16) ? 3 : 2) : Wd;
    const u16* tab = pl + (size_t)rsp * T + (size_t)(csp * 2) * T;

    u16x8 acc = {0, 0, 0, 0, 0, 0, 0, 0};   // minimum key
    for (int r = 0; r < rn; ++r) {
        const int row = rsp ? ((r == 0) ? a : (r == 1) ? (b - 8) : (a + 5))
                            : (a + r);
        const u16* rp = tab + (size_t)row * RS;
        for (int c = 0; c < cn; ++c) {
            const int col = csp ? ((c == 0) ? wa : (c == 1) ? (wb - 8) : (wa + 5))
                                : (wa + c);
            acc = kmax(acc, *(const u16x8*)(rp + (size_t)col * 32));
        }
    }

    // Stage through LDS so the global store is coalesced (2 x dwordx4/lane).
    __shared__ float lds[2048];
    float* lp = lds + (w << 9);
    #pragma unroll
    for (int i = 0; i < 8; ++i) lp[i * 64 + lane] = key_to_f32(acc[i]);
    __syncthreads();
    const float4* lp4 = (const float4*)lds + (w << 7);
    float4* ob4 = (float4*)(out + ((size_t)n * C_ + (cg << 5) + co) * (PH_ * PW_));
    ob4[lane]      = lp4[lane];
    ob4[64 + lane] = lp4[64 + lane];
}

// ---------- Fallback if ws is too small ----------
__global__ __launch_bounds__(256) void roi_pool_fallback(
    const float* __restrict__ fm, const int* __restrict__ rois,
    float* __restrict__ out, int N)
{
    const int wid  = threadIdx.x >> 6;
    const int lane = threadIdx.x & 63;
    const int bid  = blockIdx.x;
    const int xcd  = bid & 7;
    const int t    = bid >> 3;
    const int csub = t & 7;
    const int n    = t >> 3;
    if (n >= N) return;
    const int c = (xcd << 5) + (csub << 2) + wid;

    const int4 roi = ((const int4*)rois)[n];
    const int y = roi.x, x = roi.y, rH = roi.z, rW = roi.w;

    const float2* plane2 = (const float2*)(fm + (size_t)c * (H_ * W_));
    const int pw = lane & 7;
    const int j  = lane >> 3;
    const int ws = (pw * rW) >> 3;
    const int we = (((pw + 1) * rW) + 7) >> 3;

    #pragma unroll
    for (int ph = 0; ph < PH_; ++ph) {
        const int hs = (ph * rH) >> 3;
        const int he = ((ph + 1) * rH + 7) >> 3;
        const float2* p = plane2 + (size_t)(y + hs) * (W_ / 2) + lane;
        float m0 = -INFINITY, m1 = -INFINITY;
        int cnt = he - hs;
        while (cnt >= 2) {
            const float2 a = p[0];
            const float2 b = p[W_ / 2];
            p += W_; cnt -= 2;
            m0 = fmaxf(m0, fmaxf(a.x, b.x));
            m1 = fmaxf(m1, fmaxf(a.y, b.y));
        }
        if (cnt) { const float2 a = p[0]; m0 = fmaxf(m0, a.x); m1 = fmaxf(m1, a.y); }

        float rr = -INFINITY;
        #pragma unroll
        for (int k = 0; k < 3; ++k) {
            const int w  = ws + j + k * 8;
            const int wa = x + w;
            const float a = __shfl(m0, (wa >> 1) & 63, 64);
            const float b = __shfl(m1, (wa >> 1) & 63, 64);
            if (w < we) rr = fmaxf(rr, (wa & 1) ? b : a);
        }
        rr = fmaxf(rr, __shfl_xor(rr, 8, 64));
        rr = fmaxf(rr, __shfl_xor(rr, 16, 64));
        rr = fmaxf(rr, __shfl_xor(rr, 32, 64));
        if (lane < PW_) out[(((size_t)n * C_ + c) * PH_ + ph) * PW_ + lane] = rr;
    }
}

extern "C" void kernel_launch(void* const* d_in, const int* in_sizes, int n_in,
                              void* d_out, int out_size, void* d_ws, size_t ws_size,
                              hipStream_t stream) {
    const float* fm   = (const float*)d_in[0];
    const int*   rois = (const int*)d_in[1];
    float*       out  = (float*)d_out;
    const int N = in_sizes[1] / 4;

    const size_t Tel  = (size_t)HW_ * C_;            // elements per table
    const size_t need = 4 * Tel * sizeof(u16);       // 33.55 MB
    if (ws_size >= need) {
        u16* fmt = (u16*)d_ws;          // offset 0   (base keys)
        u16* m3  = fmt + Tel;           // offset T   (vertical 8)
        u16* mw  = fmt + 2 * Tel;       // offset 2T  (horizontal 8)
        u16* m8  = fmt + 3 * Tel;       // offset 3T  (2-D 8x8)
        transpose_kernel<<<dim3((HW_ / 256) * 8), 256, 0, stream>>>(fm, fmt);
        k2_kernel<<<dim3(192), 256, 0, stream>>>(fmt, m3, mw);
        k3_kernel<<<dim3(128), 256, 0, stream>>>(mw, m8);
        pool2_kernel<<<dim3(N * 8), 256, 0, stream>>>(fmt, rois, out, N);
    } else {
        roi_pool_fallback<<<dim3(64 * N), 256, 0, stream>>>(fm, rois, out, N);
    }
}

// Round 3
// 104.259 us; speedup vs baseline: 1.1350x; 1.0735x over previous
//
#include <hip/hip_runtime.h>
#include <math.h>

// Problem constants: C=256, H=W=128, PH=PW=8.
#define C_ 256
#define H_ 128
#define W_ 128
#define PH_ 8
#define PW_ 8
#define HW_ (H_ * W_)
#define M3ROWS (H_ - 8 + 1)   // 121 sliding-window rows

typedef unsigned short u16;
typedef u16 u16x4 __attribute__((ext_vector_type(4)));
typedef u16 u16x8 __attribute__((ext_vector_type(8)));

__device__ __forceinline__ u16x8 kmax(u16x8 a, u16x8 b) {
    return __builtin_elementwise_max(a, b);
}

// fp32 -> bf16 (RNE) -> monotone-mapped u16 key (unsigned order == float order)
__device__ __forceinline__ u16 f32_to_key(float f) {
    unsigned u = __float_as_uint(f);
    unsigned r = (u + 0x7fffu + ((u >> 16) & 1u)) >> 16;   // RNE to bf16
    u16 b = (u16)r;
    return (b & 0x8000u) ? (u16)~b : (u16)(b | 0x8000u);
}
__device__ __forceinline__ float key_to_f32(u16 k) {
    u16 b = (k & 0x8000u) ? (u16)(k & 0x7fffu) : (u16)~k;
    return __uint_as_float(((unsigned)b) << 16);
}

// ---------- Kernel A: transpose + keys + mw (horizontal slide-8) ----------
// Each block owns (cg, 2 full rows). Phase 1: fp32 tile. Phase 2: keys ->
// global fmt + LDS. Phase 3: mw[row][j] = max(keys[row][j..j+8)) for j<121.
__global__ __launch_bounds__(256) void transpose_mw_kernel(
    const float* __restrict__ fm, u16* __restrict__ fmt, u16* __restrict__ mw)
{
    __shared__ float tile[32 * 257];
    __shared__ u16 keys[256 * 32];       // [hw_local][ch]
    const int tid = threadIdx.x;
    const int g   = blockIdx.x & 7;
    const int hwb = blockIdx.x >> 3;
    const int c0  = g * 32;
    const int hw0 = hwb * 256;           // = (2*hwb)*W_ : 2 full rows

    const int l    = tid & 63;
    const int crow = tid >> 6;
    const int sw   = (l >> 3) & 3;
    #pragma unroll
    for (int k = 0; k < 8; ++k) {
        const int c = crow + 4 * k;
        const float4 v = *(const float4*)(fm + (size_t)(c0 + c) * HW_ + hw0 + 4 * l);
        float* t = tile + c * 257 + 4 * l;
        t[(0 + sw) & 3] = v.x;
        t[(1 + sw) & 3] = v.y;
        t[(2 + sw) & 3] = v.z;
        t[(3 + sw) & 3] = v.w;
    }
    __syncthreads();

    u16* dst = fmt + (size_t)g * HW_ * 32;
    const int cq  = tid & 7;
    const int hwr = tid >> 3;
    #pragma unroll
    for (int m = 0; m < 8; ++m) {
        const int hw = hwr + 32 * m;
        const int o  = (hw & ~3) | (((hw & 3) + m) & 3);
        u16x4 w;
        w.x = f32_to_key(tile[(4 * cq + 0) * 257 + o]);
        w.y = f32_to_key(tile[(4 * cq + 1) * 257 + o]);
        w.z = f32_to_key(tile[(4 * cq + 2) * 257 + o]);
        w.w = f32_to_key(tile[(4 * cq + 3) * 257 + o]);
        *(u16x4*)(dst + (size_t)(hw0 + hw) * 32 + 4 * cq) = w;
        *(u16x4*)(keys + hw * 32 + 4 * cq) = w;
    }
    __syncthreads();

    // Phase 3: 2 rows x 121 cols x 4 ch-octs = 968 u16x8 outputs.
    u16* mwp = mw + (size_t)g * HW_ * 32;
    const int row0 = hwb * 2;
    for (int o = tid; o < 968; o += 256) {
        const int oct  = o & 3;
        const int cell = o >> 2;          // 0..241
        const int row  = cell / 121;      // 0 or 1 (const-div -> magic mul)
        const int j    = cell - row * 121;
        const u16* kp = keys + (row * W_ + j) * 32 + oct * 8;
        u16x8 m = *(const u16x8*)kp;
        #pragma unroll
        for (int d = 1; d < 8; ++d)
            m = kmax(m, *(const u16x8*)(kp + d * 32));
        *(u16x8*)(mwp + (size_t)((row0 + row) * W_ + j) * 32 + oct * 8) = m;
    }
}

// ---------- Vertical sliding 8-row max body: dst[i] = max(src rows [i,i+8)) --
// All tables share the full [128 rows][128 cols][32 ch] layout per cg; only
// rows 0..120 of dst are written.  128 blocks: bid = (seg<<6) | (band<<3) | cg.
__device__ __forceinline__ void vslide_body(
    const u16* __restrict__ src, u16* __restrict__ dst, int bid)
{
    const int g    = bid & 7;
    const int band = (bid >> 3) & 7;
    const int seg  = bid >> 6;          // 0..1
    const int i0   = band * 16;
    const int t    = threadIdx.x;
    const int co   = (t & 3) << 3;
    const int w    = (t >> 2) + 64 * seg;

    const u16* s = src + (size_t)g * HW_ * 32;
    u16*       d = dst + (size_t)g * HW_ * 32;
    const size_t RS = (size_t)W_ * 32;
    const size_t cofs = (size_t)w * 32 + co;

    u16x8 r[8];
    #pragma unroll
    for (int k = 0; k < 7; ++k)
        r[k] = *(const u16x8*)(s + (size_t)(i0 + k) * RS + cofs);
    #pragma unroll
    for (int j = 0; j < 16; ++j) {
        const int i = i0 + j;
        if (i < M3ROWS) {
            r[(j + 7) & 7] = *(const u16x8*)(s + (size_t)(i + 7) * RS + cofs);
            u16x8 m01 = kmax(r[0], r[1]);
            u16x8 m23 = kmax(r[2], r[3]);
            u16x8 m45 = kmax(r[4], r[5]);
            u16x8 m67 = kmax(r[6], r[7]);
            *(u16x8*)(d + (size_t)i * RS + cofs) =
                kmax(kmax(m01, m23), kmax(m45, m67));
        }
    }
}

// ---------- Kernel B: m3 = vslide8(fmt)  ||  m8 = vslide8(mw) ----------
// 256 blocks (one per CU): low half -> m3, high half -> m8. Both inputs are
// complete after kernel A, so the two passes share one dispatch.
__global__ __launch_bounds__(256) void slides_kernel(
    const u16* __restrict__ fmt, const u16* __restrict__ mw,
    u16* __restrict__ m3, u16* __restrict__ m8)
{
    const int bid = blockIdx.x;
    if (bid < 128) vslide_body(fmt, m3, bid);
    else           vslide_body(mw, m8, bid - 128);
}

// ---------- Kernel C: pool — one lane = one (ph,pw) bin x 8 channels --------
// Tables at offsets {0,T,2T,3T} = {fmt, m3, mw, m8}; any bin side L:
//   L>=8 : 2 overlapping 8-spans {a, b-8} (+ a+5 if L==17)
//   L<8  : L singles
// so table = base + rsp*T + csp*2T and the bin is rn*cn loads (typ. 4).
__global__ __launch_bounds__(256) void pool2_kernel(
    const u16* __restrict__ tabs, const int* __restrict__ rois,
    float* __restrict__ out, int N)
{
    const int bid  = blockIdx.x;
    const int cg   = bid & 7;            // XCD-affine channel group
    const int n    = bid >> 3;
    const int w    = threadIdx.x >> 6;   // channel oct within cg
    const int lane = threadIdx.x & 63;
    const int ph   = lane >> 3;
    const int pw   = lane & 7;
    const int co   = w << 3;

    const int4 roi = ((const int4*)rois)[n];
    const int y = roi.x, x = roi.y, rH = roi.z, rW = roi.w;

    const int hs  = (ph * rH) >> 3;
    const int he  = ((ph + 1) * rH + 7) >> 3;
    const int ws_ = (pw * rW) >> 3;
    const int we  = ((pw + 1) * rW + 7) >> 3;
    const int a = y + hs, b = y + he, L = he - hs;     // L in [1,17]
    const int wa = x + ws_, wb = x + we, Wd = we - ws_;

    const size_t T  = (size_t)HW_ * C_;
    const size_t RS = (size_t)W_ * 32;
    const u16* pl = tabs + (size_t)cg * (HW_ * 32) + co;

    const int rsp = (L >= 8), csp = (Wd >= 8);
    const int rn = rsp ? ((L > 16) ? 3 : 2) : L;
    const int cn = csp ? ((Wd > 16) ? 3 : 2) : Wd;
    const u16* tab = pl + (size_t)rsp * T + (size_t)(csp * 2) * T;

    u16x8 acc = {0, 0, 0, 0, 0, 0, 0, 0};   // minimum key
    for (int r = 0; r < rn; ++r) {
        const int row = rsp ? ((r == 0) ? a : (r == 1) ? (b - 8) : (a + 5))
                            : (a + r);
        const u16* rp = tab + (size_t)row * RS;
        for (int c = 0; c < cn; ++c) {
            const int col = csp ? ((c == 0) ? wa : (c == 1) ? (wb - 8) : (wa + 5))
                                : (wa + c);
            acc = kmax(acc, *(const u16x8*)(rp + (size_t)col * 32));
        }
    }

    // Stage through LDS so the global store is coalesced (2 x dwordx4/lane).
    __shared__ float lds[2048];
    float* lp = lds + (w << 9);
    #pragma unroll
    for (int i = 0; i < 8; ++i) lp[i * 64 + lane] = key_to_f32(acc[i]);
    __syncthreads();
    const float4* lp4 = (const float4*)lds + (w << 7);
    float4* ob4 = (float4*)(out + ((size_t)n * C_ + (cg << 5) + co) * (PH_ * PW_));
    ob4[lane]      = lp4[lane];
    ob4[64 + lane] = lp4[64 + lane];
}

// ---------- Fallback if ws is too small ----------
__global__ __launch_bounds__(256) void roi_pool_fallback(
    const float* __restrict__ fm, const int* __restrict__ rois,
    float* __restrict__ out, int N)
{
    const int wid  = threadIdx.x >> 6;
    const int lane = threadIdx.x & 63;
    const int bid  = blockIdx.x;
    const int xcd  = bid & 7;
    const int t    = bid >> 3;
    const int csub = t & 7;
    const int n    = t >> 3;
    if (n >= N) return;
    const int c = (xcd << 5) + (csub << 2) + wid;

    const int4 roi = ((const int4*)rois)[n];
    const int y = roi.x, x = roi.y, rH = roi.z, rW = roi.w;

    const float2* plane2 = (const float2*)(fm + (size_t)c * (H_ * W_));
    const int pw = lane & 7;
    const int j  = lane >> 3;
    const int ws = (pw * rW) >> 3;
    const int we = (((pw + 1) * rW) + 7) >> 3;

    #pragma unroll
    for (int ph = 0; ph < PH_; ++ph) {
        const int hs = (ph * rH) >> 3;
        const int he = ((ph + 1) * rH + 7) >> 3;
        const float2* p = plane2 + (size_t)(y + hs) * (W_ / 2) + lane;
        float m0 = -INFINITY, m1 = -INFINITY;
        int cnt = he - hs;
        while (cnt >= 2) {
            const float2 a = p[0];
            const float2 b = p[W_ / 2];
            p += W_; cnt -= 2;
            m0 = fmaxf(m0, fmaxf(a.x, b.x));
            m1 = fmaxf(m1, fmaxf(a.y, b.y));
        }
        if (cnt) { const float2 a = p[0]; m0 = fmaxf(m0, a.x); m1 = fmaxf(m1, a.y); }

        float rr = -INFINITY;
        #pragma unroll
        for (int k = 0; k < 3; ++k) {
            const int w  = ws + j + k * 8;
            const int wa = x + w;
            const float a = __shfl(m0, (wa >> 1) & 63, 64);
            const float b = __shfl(m1, (wa >> 1) & 63, 64);
            if (w < we) rr = fmaxf(rr, (wa & 1) ? b : a);
        }
        rr = fmaxf(rr, __shfl_xor(rr, 8, 64));
        rr = fmaxf(rr, __shfl_xor(rr, 16, 64));
        rr = fmaxf(rr, __shfl_xor(rr, 32, 64));
        if (lane < PW_) out[(((size_t)n * C_ + c) * PH_ + ph) * PW_ + lane] = rr;
    }
}

extern "C" void kernel_launch(void* const* d_in, const int* in_sizes, int n_in,
                              void* d_out, int out_size, void* d_ws, size_t ws_size,
                              hipStream_t stream) {
    const float* fm   = (const float*)d_in[0];
    const int*   rois = (const int*)d_in[1];
    float*       out  = (float*)d_out;
    const int N = in_sizes[1] / 4;

    const size_t Tel  = (size_t)HW_ * C_;            // elements per table
    const size_t need = 4 * Tel * sizeof(u16);       // 33.55 MB
    if (ws_size >= need) {
        u16* fmt = (u16*)d_ws;          // offset 0   (base keys)
        u16* m3  = fmt + Tel;           // offset T   (vertical 8)
        u16* mw  = fmt + 2 * Tel;       // offset 2T  (horizontal 8)
        u16* m8  = fmt + 3 * Tel;       // offset 3T  (2-D 8x8)
        transpose_mw_kernel<<<dim3((HW_ / 256) * 8), 256, 0, stream>>>(fm, fmt, mw);
        slides_kernel<<<dim3(256), 256, 0, stream>>>(fmt, mw, m3, m8);
        pool2_kernel<<<dim3(N * 8), 256, 0, stream>>>(fmt, rois, out, N);
    } else {
        roi_pool_fallback<<<dim3(64 * N), 256, 0, stream>>>(fm, rois, out, N);
    }
}